// Round 2
// baseline (263.012 us; speedup 1.0000x reference)
//
#include <hip/hip_runtime.h>
#include <hip/hip_bf16.h>

#define NB 2
#define NN 20000
#define NKN 16          // neighbors per node
#define NC 128          // C_IN
#define NM 9            // M kernels
#define NO 128          // C_OUT
#define NR (NB*NN)      // 40000 rows
#define KK (NM*NC)      // 1152 GEMM reduce dim
#define NKC (KK/32)     // 36 K-chunks of 32

typedef short bf16x8 __attribute__((ext_vector_type(8)));
typedef float f32x4 __attribute__((ext_vector_type(4)));

// ---------------- Kernel 1: y[r][m] = dot(x[r,:], u[m,:]) ----------------
__global__ __launch_bounds__(256) void ycalc_kernel(const float* __restrict__ x,
                                                    const float* __restrict__ u,
                                                    float* __restrict__ y) {
    __shared__ float u_l[NM * NC];
    for (int t = threadIdx.x; t < NM * NC; t += 256) u_l[t] = u[t];
    __syncthreads();
    int wave = threadIdx.x >> 6;
    int lane = threadIdx.x & 63;
    int node = blockIdx.x * 4 + wave;   // grid = NR/4 exactly
    float xv0 = x[node * NC + lane];
    float xv1 = x[node * NC + 64 + lane];
    #pragma unroll
    for (int m = 0; m < NM; m++) {
        float p = xv0 * u_l[m * NC + lane] + xv1 * u_l[m * NC + 64 + lane];
        #pragma unroll
        for (int off = 32; off > 0; off >>= 1) p += __shfl_xor(p, off, 64);
        if (lane == 0) y[node * NM + m] = p;
    }
}

// ---------------- Kernel 2: per-node softmax + S' = deg_inv * sum_k q*patch (bf16) --
// one 128-thread block per (b,n); thread = channel c.
// Edge-owner threads (tid<16) compute all 9 logits + softmax for their edge.
__global__ __launch_bounds__(128) void scalc_kernel(const float* __restrict__ x,
                                                    const int* __restrict__ adj,
                                                    const float* __restrict__ y,
                                                    const float* __restrict__ cv,
                                                    __hip_bfloat16* __restrict__ Sp) {
    int node = blockIdx.x;
    int b = node / NN;
    int n = node - b * NN;
    __shared__ int s_adj[NKN];
    __shared__ float s_q[NKN][NM];
    __shared__ float s_di;
    int tid = threadIdx.x;
    if (tid < NKN) s_adj[tid] = adj[n * NKN + tid];
    if (tid == 0) {
        int d = 0;
        #pragma unroll
        for (int k = 0; k < NKN; k++) d += (adj[n * NKN + k] != 0);
        s_di = (d > 0) ? 1.f / (float)d : 0.f;
    }
    __syncthreads();
    if (tid < NKN) {                      // edge k = tid: logits (Y-trick) + softmax over m
        int a = s_adj[tid];
        float l[NM];
        #pragma unroll
        for (int m = 0; m < NM; m++) {
            float ya = (a == 0) ? 0.f : y[(b * NN + (a - 1)) * NM + m];
            l[m] = y[node * NM + m] - ya + cv[m];
        }
        float mx = l[0];
        #pragma unroll
        for (int m = 1; m < NM; m++) mx = fmaxf(mx, l[m]);
        float e[NM]; float sum = 0.f;
        #pragma unroll
        for (int m = 0; m < NM; m++) { e[m] = expf(l[m] - mx); sum += e[m]; }
        float inv = 1.f / sum;
        #pragma unroll
        for (int m = 0; m < NM; m++) s_q[tid][m] = e[m] * inv;
    }
    __syncthreads();
    float s[NM];
    #pragma unroll
    for (int m = 0; m < NM; m++) s[m] = 0.f;
    #pragma unroll
    for (int k = 0; k < NKN; k++) {
        int a = s_adj[k];                 // wave-uniform branch
        float p = (a == 0) ? 0.f : x[(b * NN + (a - 1)) * NC + tid];
        #pragma unroll
        for (int m = 0; m < NM; m++) s[m] += s_q[k][m] * p;  // q broadcast from LDS
    }
    float di = s_di;
    #pragma unroll
    for (int m = 0; m < NM; m++)
        Sp[(long)node * KK + m * NC + tid] = __float2bfloat16(s[m] * di);
}

// ---------------- Kernel 3: W[m][o][c] f32 -> Wg bf16, B-fragment-friendly layout ---
// Wg[((kk/32)*128 + o)*32 + (kk%32)] = W[m][o][c],  kk = m*128 + c
__global__ __launch_bounds__(256) void wprep_kernel(const float* __restrict__ W,
                                                    __hip_bfloat16* __restrict__ Wg) {
    int t = blockIdx.x * 256 + threadIdx.x;   // t < 1152*128
    int kk = t >> 7;
    int o = t & 127;
    int m = kk >> 7;
    int c = kk & 127;
    float v = W[m * 16384 + o * 128 + c];
    Wg[((kk >> 5) * 128 + o) * 32 + (kk & 31)] = __float2bfloat16(v);
}

// ---------------- Kernel 4: out[r][o] = sum_kk Sp[r][kk]*Wg[kk][o] + b[o] ----------
// Register-only MFMA GEMM: 4 waves/block, wave = 16 rows x 128 cols, no LDS.
__global__ __launch_bounds__(256) void gemm_kernel(const __hip_bfloat16* __restrict__ Sp,
                                                   const __hip_bfloat16* __restrict__ Wg,
                                                   const float* __restrict__ bv,
                                                   float* __restrict__ out) {
    int wave = threadIdx.x >> 6;
    int lane = threadIdx.x & 63;
    int lr = lane & 15;       // A row in strip / B col in tile
    int quad = lane >> 4;     // k-group
    int row_base = blockIdx.x * 64 + wave * 16;
    f32x4 acc[8];
    #pragma unroll
    for (int ct = 0; ct < 8; ct++) acc[ct] = (f32x4){0.f, 0.f, 0.f, 0.f};
    const short* sp = reinterpret_cast<const short*>(Sp);
    const short* wg = reinterpret_cast<const short*>(Wg);
    long a_off = (long)(row_base + lr) * KK + quad * 8;
    for (int kc = 0; kc < NKC; kc++) {
        bf16x8 afrag = *reinterpret_cast<const bf16x8*>(sp + a_off + kc * 32);
        #pragma unroll
        for (int ct = 0; ct < 8; ct++) {
            bf16x8 bfrag = *reinterpret_cast<const bf16x8*>(
                wg + ((kc * 128) + ct * 16 + lr) * 32 + quad * 8);
            acc[ct] = __builtin_amdgcn_mfma_f32_16x16x32_bf16(afrag, bfrag, acc[ct], 0, 0, 0);
        }
    }
    #pragma unroll
    for (int ct = 0; ct < 8; ct++) {
        int col = ct * 16 + lr;
        float bb = bv[col];
        #pragma unroll
        for (int r = 0; r < 4; r++) {
            int row = row_base + quad * 4 + r;   // D: row = quad*4 + reg, col = lane&15
            out[(long)row * NO + col] = acc[ct][r] + bb;
        }
    }
}

extern "C" void kernel_launch(void* const* d_in, const int* in_sizes, int n_in,
                              void* d_out, int out_size, void* d_ws, size_t ws_size,
                              hipStream_t stream) {
    const float* x   = (const float*)d_in[0];   // (B,N,C)
    const int*   adj = (const int*)  d_in[1];   // (N,K)
    const float* W   = (const float*)d_in[2];   // (M,O,C)
    const float* bv  = (const float*)d_in[3];   // (O,)
    const float* u   = (const float*)d_in[4];   // (M,C)
    const float* cv  = (const float*)d_in[5];   // (M,)
    float* out = (float*)d_out;

    char* ws = (char*)d_ws;
    float* y = (float*)ws;                                        // 40000*9*4   = 1,440,000 B (16B aligned)
    __hip_bfloat16* Sp = (__hip_bfloat16*)(ws + 1440000);         // 40000*1152*2 = 92,160,000 B
    __hip_bfloat16* Wg = (__hip_bfloat16*)(ws + 1440000 + 92160000); // 294,912 B

    ycalc_kernel<<<NR / 4, 256, 0, stream>>>(x, u, y);
    scalc_kernel<<<NR, 128, 0, stream>>>(x, adj, y, cv, Sp);
    wprep_kernel<<<(KK * NO) / 256, 256, 0, stream>>>(W, Wg);
    gemm_kernel<<<NR / 64, 256, 0, stream>>>(Sp, Wg, bv, out);
}

// Round 3
// 170.086 us; speedup vs baseline: 1.5463x; 1.5463x over previous
//
#include <hip/hip_runtime.h>
#include <hip/hip_bf16.h>

#define NB 2
#define NN 20000
#define NKN 16          // neighbors per node
#define NC 128          // C_IN
#define NM 9            // M kernels
#define NO 128          // C_OUT
#define NR (NB*NN)      // 40000 rows
#define KK (NM*NC)      // 1152 GEMM reduce dim
#define NKC (KK/32)     // 36 K-chunks of 32

#define AS1 __attribute__((address_space(1)))
#define AS3 __attribute__((address_space(3)))

typedef short bf16x8 __attribute__((ext_vector_type(8)));
typedef float f32x4 __attribute__((ext_vector_type(4)));

__device__ inline float bf2f(unsigned short h) {
    union { unsigned int u; float f; } v; v.u = ((unsigned int)h) << 16; return v.f;
}

// ---------------- Kernel 1: y[r][m] = dot(x[r,:], u[m,:]); optionally emit xb = bf16(x) --
__global__ __launch_bounds__(256) void ycalc_kernel(const float* __restrict__ x,
                                                    const float* __restrict__ u,
                                                    float* __restrict__ y,
                                                    __hip_bfloat16* __restrict__ xb) {
    __shared__ float u_l[NM * NC];
    for (int t = threadIdx.x; t < NM * NC; t += 256) u_l[t] = u[t];
    __syncthreads();
    int wave = threadIdx.x >> 6;
    int lane = threadIdx.x & 63;
    int node = blockIdx.x * 4 + wave;   // grid = NR/4 exactly
    float xv0 = x[node * NC + lane];
    float xv1 = x[node * NC + 64 + lane];
    if (xb != nullptr) {                // wave-uniform branch
        xb[node * NC + lane]      = __float2bfloat16(xv0);
        xb[node * NC + 64 + lane] = __float2bfloat16(xv1);
    }
    #pragma unroll
    for (int m = 0; m < NM; m++) {
        float p = xv0 * u_l[m * NC + lane] + xv1 * u_l[m * NC + 64 + lane];
        #pragma unroll
        for (int off = 32; off > 0; off >>= 1) p += __shfl_xor(p, off, 64);
        if (lane == 0) y[node * NM + m] = p;
    }
}

// ---------------- Kernel 2: per-node softmax + S' = deg_inv * sum_k q*patch (bf16) --
// 256 threads = 8 nodes/block; phase3 thread = (node sub-idx, 4 channels).
template<bool BF16G>
__global__ __launch_bounds__(256) void scalc_kernel(const float* __restrict__ x,
                                                    const __hip_bfloat16* __restrict__ xb,
                                                    const int* __restrict__ adj,
                                                    const float* __restrict__ y,
                                                    const float* __restrict__ cv,
                                                    __hip_bfloat16* __restrict__ Sp) {
    int node0 = blockIdx.x * 8;           // NN % 8 == 0 -> block never straddles batch b
    int tid = threadIdx.x;
    __shared__ int   s_adj[8][NKN];
    __shared__ float s_q[8][NKN][12];     // 9 used, padded to 48B rows for b128 reads
    __shared__ float s_di[8];

    if (tid < 128) {                      // phase 1: load adj (8 nodes x 16)
        int ln = tid >> 4, k = tid & 15;
        int n = (node0 + ln) % NN;
        s_adj[ln][k] = adj[n * NKN + k];
    }
    __syncthreads();

    if (tid < 128) {                      // phase 2: logits (Y-trick) + softmax per edge
        int ln = tid >> 4, k = tid & 15;
        int node = node0 + ln;
        int b = node / NN;
        int a = s_adj[ln][k];
        const float* yn = y + node * NM;
        float l[NM];
        if (a != 0) {
            const float* ya = y + (long)(b * NN + a - 1) * NM;
            #pragma unroll
            for (int m = 0; m < NM; m++) l[m] = yn[m] - ya[m] + cv[m];
        } else {
            #pragma unroll
            for (int m = 0; m < NM; m++) l[m] = yn[m] + cv[m];
        }
        float mx = l[0];
        #pragma unroll
        for (int m = 1; m < NM; m++) mx = fmaxf(mx, l[m]);
        float e[NM]; float sum = 0.f;
        #pragma unroll
        for (int m = 0; m < NM; m++) { e[m] = expf(l[m] - mx); sum += e[m]; }
        float inv = 1.f / sum;
        #pragma unroll
        for (int m = 0; m < NM; m++) s_q[ln][k][m] = e[m] * inv;
    } else if (tid < 136) {               // 8 threads: degree
        int ln = tid - 128;
        int d = 0;
        #pragma unroll
        for (int k = 0; k < NKN; k++) d += (s_adj[ln][k] != 0);
        s_di[ln] = (d > 0) ? 1.f / (float)d : 0.f;
    }
    __syncthreads();

    // phase 3: accumulate s[m][0..3] over 16 neighbors, 4 channels per thread
    int ln = tid >> 5;                    // node sub-idx (32 threads each)
    int c4 = (tid & 31) << 2;             // channel base
    int node = node0 + ln;
    int b = node / NN;
    float s[NM][4];
    #pragma unroll
    for (int m = 0; m < NM; m++)
        #pragma unroll
        for (int j = 0; j < 4; j++) s[m][j] = 0.f;

    #pragma unroll
    for (int k = 0; k < NKN; k++) {
        int a = s_adj[ln][k];             // uniform across the 32-lane node group
        if (a != 0) {
            float p0, p1, p2, p3;
            if (BF16G) {
                ushort4 pv = *(const ushort4*)((const unsigned short*)xb +
                                               (long)(b * NN + a - 1) * NC + c4);
                p0 = bf2f(pv.x); p1 = bf2f(pv.y); p2 = bf2f(pv.z); p3 = bf2f(pv.w);
            } else {
                float4 pv = *(const float4*)(x + (long)(b * NN + a - 1) * NC + c4);
                p0 = pv.x; p1 = pv.y; p2 = pv.z; p3 = pv.w;
            }
            float q[NM];
            #pragma unroll
            for (int m = 0; m < NM; m++) q[m] = s_q[ln][k][m];
            #pragma unroll
            for (int m = 0; m < NM; m++) {
                s[m][0] += q[m] * p0; s[m][1] += q[m] * p1;
                s[m][2] += q[m] * p2; s[m][3] += q[m] * p3;
            }
        }
    }
    float di = s_di[ln];
    #pragma unroll
    for (int m = 0; m < NM; m++) {
        __hip_bfloat16 ov[4];
        #pragma unroll
        for (int j = 0; j < 4; j++) ov[j] = __float2bfloat16(s[m][j] * di);
        *(ushort4*)((unsigned short*)Sp + (long)node * KK + m * NC + c4) = *(ushort4*)ov;
    }
}

// ---------------- Kernel 3: W[m][o][c] f32 -> Wg bf16, B-fragment-friendly layout ---
// Wg[((kk/32)*128 + o)*32 + (kk%32)] = W[m][o][c],  kk = m*128 + c
__global__ __launch_bounds__(256) void wprep_kernel(const float* __restrict__ W,
                                                    __hip_bfloat16* __restrict__ Wg) {
    int t = blockIdx.x * 256 + threadIdx.x;   // t < 1152*128
    int kk = t >> 7;
    int o = t & 127;
    int m = kk >> 7;
    int c = kk & 127;
    float v = W[m * 16384 + o * 128 + c];
    Wg[((kk >> 5) * 128 + o) * 32 + (kk & 31)] = __float2bfloat16(v);
}

// ---------------- Kernel 4: out[r][o] = sum_kk Sp[r][kk]*Wg[kk][o] + b[o] ----------
// MFMA GEMM: 4 waves/block = 64 rows; B k-chunk (8KB) staged in LDS via
// global_load_lds (width 16), double-buffered, shared by all 4 waves.
__global__ __launch_bounds__(256) void gemm_kernel(const __hip_bfloat16* __restrict__ Sp,
                                                   const __hip_bfloat16* __restrict__ Wg,
                                                   const float* __restrict__ bv,
                                                   float* __restrict__ out) {
    __shared__ __align__(16) short sB[2][4096];   // 2 x 8KB: 128 cols x 32 k, bf16
    int tid = threadIdx.x;
    int wave = tid >> 6;
    int lane = tid & 63;
    int lr = lane & 15;       // A row in strip / B col in tile
    int quad = lane >> 4;     // k-group
    int row_base = blockIdx.x * 64 + wave * 16;
    const short* sp = reinterpret_cast<const short*>(Sp);
    const short* wg = reinterpret_cast<const short*>(Wg);

    f32x4 acc[8];
    #pragma unroll
    for (int ct = 0; ct < 8; ct++) acc[ct] = (f32x4){0.f, 0.f, 0.f, 0.f};
    long a_off = (long)(row_base + lr) * KK + quad * 8;

    // stage B chunk kc into buf: each wave DMAs its 2KB segment (2 x 1KB calls)
    auto stage = [&](int kc, int buf) {
        #pragma unroll
        for (int sub = 0; sub < 2; sub++) {
            const short* src = wg + kc * 4096 + wave * 1024 + sub * 512 + lane * 8;
            __builtin_amdgcn_global_load_lds((const AS1 void*)src,
                                             (AS3 void*)&sB[buf][wave * 1024 + sub * 512],
                                             16, 0, 0);
        }
    };

    stage(0, 0);
    bf16x8 afrag = *reinterpret_cast<const bf16x8*>(sp + a_off);
    __syncthreads();                       // barrier drains vmcnt(0): chunk 0 ready

    for (int kc = 0; kc < NKC; kc++) {
        int buf = kc & 1;
        if (kc + 1 < NKC) stage(kc + 1, buf ^ 1);
        int kn = (kc + 1 < NKC) ? kc + 1 : kc;
        bf16x8 anext = *reinterpret_cast<const bf16x8*>(sp + a_off + (long)kn * 32);
        #pragma unroll
        for (int ct = 0; ct < 8; ct++) {
            bf16x8 bfrag = *reinterpret_cast<const bf16x8*>(&sB[buf][(ct * 16 + lr) * 32 + quad * 8]);
            acc[ct] = __builtin_amdgcn_mfma_f32_16x16x32_bf16(afrag, bfrag, acc[ct], 0, 0, 0);
        }
        afrag = anext;
        __syncthreads();                   // readers done with buf; prefetch into buf^1 drained
    }

    #pragma unroll
    for (int ct = 0; ct < 8; ct++) {
        int col = ct * 16 + lr;
        float bb = bv[col];
        #pragma unroll
        for (int r = 0; r < 4; r++) {
            int row = row_base + quad * 4 + r;   // D: row = quad*4 + reg, col = lane&15
            out[(long)row * NO + col] = acc[ct][r] + bb;
        }
    }
}

extern "C" void kernel_launch(void* const* d_in, const int* in_sizes, int n_in,
                              void* d_out, int out_size, void* d_ws, size_t ws_size,
                              hipStream_t stream) {
    const float* x   = (const float*)d_in[0];   // (B,N,C)
    const int*   adj = (const int*)  d_in[1];   // (N,K)
    const float* W   = (const float*)d_in[2];   // (M,O,C)
    const float* bv  = (const float*)d_in[3];   // (O,)
    const float* u   = (const float*)d_in[4];   // (M,C)
    const float* cv  = (const float*)d_in[5];   // (M,)
    float* out = (float*)d_out;

    char* ws = (char*)d_ws;
    float* y = (float*)ws;                                        // 1,440,000 B
    __hip_bfloat16* Sp = (__hip_bfloat16*)(ws + 1440000);         // 92,160,000 B
    __hip_bfloat16* Wg = (__hip_bfloat16*)(ws + 93600000);        //    294,912 B
    __hip_bfloat16* xb = (__hip_bfloat16*)(ws + 93894912);        // 10,240,000 B (optional)
    bool use_bf16_gather = (ws_size >= (size_t)104134912);

    ycalc_kernel<<<NR / 4, 256, 0, stream>>>(x, u, y, use_bf16_gather ? xb : nullptr);
    if (use_bf16_gather)
        scalc_kernel<true><<<NR / 8, 256, 0, stream>>>(x, xb, adj, y, cv, Sp);
    else
        scalc_kernel<false><<<NR / 8, 256, 0, stream>>>(x, xb, adj, y, cv, Sp);
    wprep_kernel<<<(KK * NO) / 256, 256, 0, stream>>>(W, Wg);
    gemm_kernel<<<NR / 64, 256, 0, stream>>>(Sp, Wg, bv, out);
}